// Round 1
// baseline (1116.345 us; speedup 1.0000x reference)
//
#include <hip/hip_runtime.h>
#include <cstdint>
#include <cstddef>

// ---------------------------------------------------------------------------
// Graph U-Net (N=4096, F=64, DEPTH=3, ratio 0.5) forward on gfx950.
// All math fp32 except the _augment matmuls, which use bf16 MFMA:
// adjacency entries are exact small integers at every level, so bf16 inputs +
// fp32 MFMA accumulation are EXACT for levels 0/1 (the ones that feed TopK
// scores); level-2 rounding (~0.4%) happens after the last pooling decision.
// ---------------------------------------------------------------------------

typedef float  f4v    __attribute__((ext_vector_type(4)));
typedef float  f32x4  __attribute__((ext_vector_type(4)));
typedef __bf16 bf16x8 __attribute__((ext_vector_type(8)));

#define NN0 4096
#define NN1 2048
#define NN2 1024
#define NN3 512

// ---------------- deg/dinv: dinv[i] = 1/sqrt(sum_j A[i,j] + 2) -------------
__global__ __launch_bounds__(256) void k_dinv(const float* __restrict__ A,
                                              float* __restrict__ dinv, int n) {
    int row = blockIdx.x;
    const float* ar = A + (size_t)row * n;
    float s = 0.f;
    for (int j = threadIdx.x; j < n; j += 256) s += ar[j];
#pragma unroll
    for (int off = 32; off > 0; off >>= 1) s += __shfl_xor(s, off);
    __shared__ float red[4];
    if ((threadIdx.x & 63) == 0) red[threadIdx.x >> 6] = s;
    __syncthreads();
    if (threadIdx.x == 0) {
        float deg = red[0] + red[1] + red[2] + red[3] + 2.0f;
        dinv[row] = (deg > 0.f) ? (1.0f / sqrtf(deg)) : 0.f;
    }
}

// ---------------- zs = dinv[i] * (X @ W), X n x 64, W 64 x 64 --------------
__global__ __launch_bounds__(256) void k_zs(const float* __restrict__ X,
                                            const float* __restrict__ W,
                                            const float* __restrict__ dinv,
                                            float* __restrict__ zs, int n) {
    __shared__ float Ws[64][65];
    __shared__ float Xs[4][64];
    int tid = threadIdx.x;
#pragma unroll
    for (int q = 0; q < 16; q++) {
        int idx = q * 256 + tid;
        Ws[idx >> 6][idx & 63] = W[idx];
    }
    int row0 = blockIdx.x << 2;
    Xs[tid >> 6][tid & 63] = X[((size_t)row0 << 6) + tid];
    __syncthreads();
    int r = tid >> 6, f = tid & 63;
    float acc = 0.f;
#pragma unroll
    for (int k = 0; k < 64; k++) acc = fmaf(Xs[r][k], Ws[k][f], acc);
    zs[((size_t)(row0 + r) << 6) + f] = dinv[row0 + r] * acc;
}

// ---------------- prop: ypart[ks] = A[64 rows, k-chunk] @ zs ---------------
// grid (n/64, 4). Deterministic split-K into 4 partial buffers.
__global__ __launch_bounds__(256) void k_prop(const float* __restrict__ A,
                                              const float* __restrict__ zs,
                                              float* __restrict__ ypart, int n) {
    int rb = blockIdx.x, ks = blockIdx.y;
    int chunk = n >> 2;
    int j0 = ks * chunk;
    __shared__ float AtT[64][68];   // transposed A tile: AtT[k][row]
    __shared__ float Zt[64][68];    // Zt[k][f]
    int tid = threadIdx.x;
    int lr = tid >> 2;              // 0..63
    int lc = (tid & 3) << 4;        // 0,16,32,48
    int ty = tid >> 4, tx = tid & 15;
    float acc[4][4] = {};
    const float* Arow = A + (size_t)(rb * 64 + lr) * n;
    for (int jt = j0; jt < j0 + chunk; jt += 64) {
#pragma unroll
        for (int q = 0; q < 4; q++) {
            f4v av = *(const f4v*)(Arow + jt + lc + (q << 2));
#pragma unroll
            for (int e = 0; e < 4; e++) AtT[lc + (q << 2) + e][lr] = av[e];
        }
#pragma unroll
        for (int q = 0; q < 4; q++) {
            f4v zv = *(const f4v*)(zs + (((size_t)(jt + lr)) << 6) + lc + (q << 2));
            *(f4v*)&Zt[lr][lc + (q << 2)] = zv;
        }
        __syncthreads();
#pragma unroll 4
        for (int k = 0; k < 64; k++) {
            f4v a4 = *(const f4v*)&AtT[k][ty << 2];
            f4v z4 = *(const f4v*)&Zt[k][tx << 2];
#pragma unroll
            for (int r = 0; r < 4; r++)
#pragma unroll
                for (int c = 0; c < 4; c++)
                    acc[r][c] = fmaf(a4[r], z4[c], acc[r][c]);
        }
        __syncthreads();
    }
    float* yp = ypart + ((size_t)ks * n << 6);
#pragma unroll
    for (int r = 0; r < 4; r++) {
        f4v o; o[0] = acc[r][0]; o[1] = acc[r][1]; o[2] = acc[r][2]; o[3] = acc[r][3];
        *(f4v*)(yp + (((size_t)(rb * 64 + (ty << 2) + r)) << 6) + (tx << 2)) = o;
    }
}

// ---------------- epilogue: H = act(dinv*(sum ypart + 2 zs) + b) -----------
__global__ __launch_bounds__(256) void k_epi(const float* __restrict__ ypart,
                                             const float* __restrict__ zs,
                                             const float* __restrict__ dinv,
                                             const float* __restrict__ b,
                                             float* __restrict__ H, int n, int relu) {
    int idx = blockIdx.x * 256 + threadIdx.x;
    int total = n << 6;
    if (idx >= total) return;
    int i = idx >> 6, f = idx & 63;
    size_t stride = (size_t)n << 6;
    float y = ypart[idx] + ypart[stride + idx] + ypart[2 * stride + idx] + ypart[3 * stride + idx];
    float v = dinv[i] * (y + 2.0f * zs[idx]) + b[f];
    if (relu) v = fmaxf(v, 0.f);
    H[idx] = v;
}

// ---------------- augment: C = (A+I)^2 with zero diag (bf16 MFMA) ----------
// A symmetric n x n fp32. grid (n/64, n/64), 256 threads (4 waves, each 32x32).
__global__ __launch_bounds__(256) void k_aug(const float* __restrict__ A,
                                             float* __restrict__ C, int n) {
    __shared__ __bf16 As[64][40];   // rows of M = A+I for the M-band (pad to 40)
    __shared__ __bf16 Bs[64][40];   // rows of M for the N-band (B via symmetry)
    int tid = threadIdx.x;
    int bm = blockIdx.x, bn = blockIdx.y;
    int wave = tid >> 6, lane = tid & 63;
    int wm = (wave >> 1) << 5, wn = (wave & 1) << 5;
    int quad = lane >> 4, l16 = lane & 15;
    int lr = tid >> 2;              // 0..63
    int lk = (tid & 3) << 3;        // 0,8,16,24
    f32x4 acc[2][2] = {};
    int grA = bm * 64 + lr;
    int grB = bn * 64 + lr;
    const float* pA = A + (size_t)grA * n;
    const float* pB = A + (size_t)grB * n;
    for (int k0 = 0; k0 < n; k0 += 32) {
        int c0 = k0 + lk;
        {
            f4v a0 = *(const f4v*)(pA + c0);
            f4v a1 = *(const f4v*)(pA + c0 + 4);
            bf16x8 t;
#pragma unroll
            for (int j = 0; j < 4; j++) {
                float v = a0[j]; if (grA == c0 + j) v += 1.0f; t[j] = (__bf16)v;
            }
#pragma unroll
            for (int j = 0; j < 4; j++) {
                float v = a1[j]; if (grA == c0 + 4 + j) v += 1.0f; t[4 + j] = (__bf16)v;
            }
            *(bf16x8*)&As[lr][lk] = t;
        }
        {
            f4v b0 = *(const f4v*)(pB + c0);
            f4v b1 = *(const f4v*)(pB + c0 + 4);
            bf16x8 t;
#pragma unroll
            for (int j = 0; j < 4; j++) {
                float v = b0[j]; if (grB == c0 + j) v += 1.0f; t[j] = (__bf16)v;
            }
#pragma unroll
            for (int j = 0; j < 4; j++) {
                float v = b1[j]; if (grB == c0 + 4 + j) v += 1.0f; t[4 + j] = (__bf16)v;
            }
            *(bf16x8*)&Bs[lr][lk] = t;
        }
        __syncthreads();
#pragma unroll
        for (int im = 0; im < 2; im++) {
            bf16x8 af = *(const bf16x8*)&As[wm + (im << 4) + l16][quad << 3];
#pragma unroll
            for (int in2 = 0; in2 < 2; in2++) {
                bf16x8 bfm = *(const bf16x8*)&Bs[wn + (in2 << 4) + l16][quad << 3];
                acc[im][in2] = __builtin_amdgcn_mfma_f32_16x16x32_bf16(af, bfm, acc[im][in2], 0, 0, 0);
            }
        }
        __syncthreads();
    }
    // C/D layout: col = lane&15, row = quad*4 + reg
#pragma unroll
    for (int im = 0; im < 2; im++)
#pragma unroll
        for (int in2 = 0; in2 < 2; in2++)
#pragma unroll
            for (int r = 0; r < 4; r++) {
                int row = bm * 64 + wm + (im << 4) + (quad << 2) + r;
                int col = bn * 64 + wn + (in2 << 4) + l16;
                C[(size_t)row * n + col] = (row == col) ? 0.f : acc[im][in2][r];
            }
}

// ---------------- scores: tanh((h . p)/||p||) ------------------------------
__global__ __launch_bounds__(256) void k_score(const float* __restrict__ H,
                                               const float* __restrict__ p,
                                               float* __restrict__ score, int n) {
    int wave = threadIdx.x >> 6, lane = threadIdx.x & 63;
    int row = (blockIdx.x << 2) + wave;
    float pv = p[lane];
    float hv = H[((size_t)row << 6) + lane];
    float d = hv * pv;
    float q = pv * pv;
#pragma unroll
    for (int off = 32; off > 0; off >>= 1) {
        d += __shfl_xor(d, off);
        q += __shfl_xor(q, off);
    }
    if (lane == 0) score[row] = tanhf(d / sqrtf(q));
}

// ---------------- top-k by exact rank (stable descending, jax semantics) ---
__global__ __launch_bounds__(256) void k_topk(const float* __restrict__ score,
                                              int* __restrict__ perm, int n, int k) {
    int i = blockIdx.x * 256 + threadIdx.x;
    float si = score[i];
    __shared__ float sc[256];
    int cnt = 0;
    for (int j0 = 0; j0 < n; j0 += 256) {
        sc[threadIdx.x] = score[j0 + threadIdx.x];
        __syncthreads();
#pragma unroll 8
        for (int t = 0; t < 256; t++) {
            float sj = sc[t];
            int j = j0 + t;
            cnt += ((sj > si) || (sj == si && j < i)) ? 1 : 0;
        }
        __syncthreads();
    }
    if (cnt < k) perm[cnt] = i;
}

// ---------------- pooled features: HP[r] = H[perm[r]] * score[perm[r]] -----
__global__ __launch_bounds__(256) void k_poolx(const float* __restrict__ H,
                                               const float* __restrict__ score,
                                               const int* __restrict__ perm,
                                               float* __restrict__ HP) {
    int idx = blockIdx.x * 256 + threadIdx.x;
    int r = idx >> 6, f = idx & 63;
    int src = perm[r];
    HP[idx] = H[((size_t)src << 6) + f] * score[src];
}

// ---------------- pooled adjacency: Anew = Aug[perm][:,perm] ---------------
__global__ __launch_bounds__(256) void k_pooladj(const float* __restrict__ Aug,
                                                 const int* __restrict__ perm,
                                                 float* __restrict__ Anew,
                                                 int kbits, int nold) {
    int idx = blockIdx.x * 256 + threadIdx.x;
    int r = idx >> kbits, c = idx & ((1 << kbits) - 1);
    Anew[idx] = Aug[(size_t)perm[r] * nold + perm[c]];
}

// ---------------- copy / scatter-add (unpool) ------------------------------
__global__ __launch_bounds__(256) void k_copy(const float* __restrict__ s,
                                              float* __restrict__ d) {
    int idx = blockIdx.x * 256 + threadIdx.x;
    d[idx] = s[idx];
}
__global__ __launch_bounds__(256) void k_scatter(const float* __restrict__ hs,
                                                 const int* __restrict__ perm,
                                                 float* __restrict__ buf) {
    int idx = blockIdx.x * 256 + threadIdx.x;
    int r = idx >> 6, f = idx & 63;
    buf[((size_t)perm[r] << 6) + f] += hs[idx];   // perm rows unique: no atomics
}

// ---------------- final: out = relu(h)/(1-prob) @ fc_w + fc_b --------------
__global__ __launch_bounds__(256) void k_final(const float* __restrict__ H,
                                               const float* __restrict__ prob,
                                               const float* __restrict__ fcw,
                                               const float* __restrict__ fcb,
                                               float* __restrict__ out, int n) {
    int wave = threadIdx.x >> 6, lane = threadIdx.x & 63;
    int row = (blockIdx.x << 2) + wave;
    float scale = 1.0f / (1.0f - prob[0]);
    float h = fmaxf(H[((size_t)row << 6) + lane], 0.f);
    float v = h * fcw[lane];
#pragma unroll
    for (int off = 32; off > 0; off >>= 1) v += __shfl_xor(v, off);
    if (lane == 0) out[row] = v * scale + fcb[0];
}

// ===========================================================================
extern "C" void kernel_launch(void* const* d_in, const int* in_sizes, int n_in,
                              void* d_out, int out_size, void* d_ws, size_t ws_size,
                              hipStream_t stream) {
    (void)in_sizes; (void)n_in; (void)out_size;
    const float* x     = (const float*)d_in[0];
    const float* adj   = (const float*)d_in[1];
    const float* prob  = (const float*)d_in[2];
    const float* downW = (const float*)d_in[3];   // 4 x 64 x 64
    const float* downb = (const float*)d_in[4];   // 4 x 64
    const float* poolw = (const float*)d_in[5];   // 3 x 64
    const float* upW   = (const float*)d_in[6];   // 3 x 64 x 64
    const float* upb   = (const float*)d_in[7];   // 3 x 64
    const float* fcw   = (const float*)d_in[8];   // 64
    const float* fcb   = (const float*)d_in[9];   // 1

    char* ws = (char*)d_ws;
    // workspace layout (bytes)
    float* AUG   = (float*)(ws + 0);            // 64 MB (4096^2)
    float* A1    = (float*)(ws + 67108864);     // 16 MB
    float* A2    = (float*)(ws + 83886080);     // 4 MB
    float* A3    = (float*)(ws + 88080384);     // 1 MB
    float* H0    = (float*)(ws + 89128960);     // 1 MB
    float* H1    = (float*)(ws + 90177536);     // 512 KB
    float* H2    = (float*)(ws + 90701824);     // 256 KB
    float* H3    = (float*)(ws + 90963968);     // 128 KB
    float* HP    = (float*)(ws + 91095040);     // 512 KB
    float* ZS    = (float*)(ws + 91619328);     // 1 MB
    float* YP    = (float*)(ws + 92667904);     // 4 MB (4-way split-K partials)
    float* UIN   = (float*)(ws + 96862208);     // 1 MB
    float* UOUT  = (float*)(ws + 97910784);     // 1 MB
    float* DINV  = (float*)(ws + 98959360);     // 16 KB
    float* SCORE = (float*)(ws + 98975744);     // 16 KB
    int*   PERM0 = (int*)(ws + 98992128);       // 8 KB
    int*   PERM1 = (int*)(ws + 99000320);       // 4 KB
    int*   PERM2 = (int*)(ws + 99004416);       // 2 KB
    if (ws_size < (size_t)99006464) return;     // insufficient scratch: bail loudly

    auto gcn = [&](const float* A, int n, const float* Xin, const float* W,
                   const float* b, float* Hout, int relu) {
        k_dinv<<<n, 256, 0, stream>>>(A, DINV, n);
        k_zs<<<n / 4, 256, 0, stream>>>(Xin, W, DINV, ZS, n);
        k_prop<<<dim3(n / 64, 4), 256, 0, stream>>>(A, ZS, YP, n);
        k_epi<<<(n * 64) / 256, 256, 0, stream>>>(YP, ZS, DINV, b, Hout, n, relu);
    };

    // ---------------- down sweep ----------------
    gcn(adj, NN0, x, downW, downb, H0, 1);

    // level 0 -> 1
    k_aug<<<dim3(NN0 / 64, NN0 / 64), 256, 0, stream>>>(adj, AUG, NN0);
    k_score<<<NN0 / 4, 256, 0, stream>>>(H0, poolw + 0, SCORE, NN0);
    k_topk<<<NN0 / 256, 256, 0, stream>>>(SCORE, PERM0, NN0, NN1);
    k_poolx<<<(NN1 * 64) / 256, 256, 0, stream>>>(H0, SCORE, PERM0, HP);
    k_pooladj<<<(NN1 * NN1) / 256, 256, 0, stream>>>(AUG, PERM0, A1, 11, NN0);
    gcn(A1, NN1, HP, downW + 4096, downb + 64, H1, 1);

    // level 1 -> 2
    k_aug<<<dim3(NN1 / 64, NN1 / 64), 256, 0, stream>>>(A1, AUG, NN1);
    k_score<<<NN1 / 4, 256, 0, stream>>>(H1, poolw + 64, SCORE, NN1);
    k_topk<<<NN1 / 256, 256, 0, stream>>>(SCORE, PERM1, NN1, NN2);
    k_poolx<<<(NN2 * 64) / 256, 256, 0, stream>>>(H1, SCORE, PERM1, HP);
    k_pooladj<<<(NN2 * NN2) / 256, 256, 0, stream>>>(AUG, PERM1, A2, 10, NN1);
    gcn(A2, NN2, HP, downW + 2 * 4096, downb + 2 * 64, H2, 1);

    // level 2 -> 3
    k_aug<<<dim3(NN2 / 64, NN2 / 64), 256, 0, stream>>>(A2, AUG, NN2);
    k_score<<<NN2 / 4, 256, 0, stream>>>(H2, poolw + 128, SCORE, NN2);
    k_topk<<<NN2 / 256, 256, 0, stream>>>(SCORE, PERM2, NN2, NN3);
    k_poolx<<<(NN3 * 64) / 256, 256, 0, stream>>>(H2, SCORE, PERM2, HP);
    k_pooladj<<<(NN3 * NN3) / 256, 256, 0, stream>>>(AUG, PERM2, A3, 9, NN2);
    gcn(A3, NN3, HP, downW + 3 * 4096, downb + 3 * 64, H3, 1);

    // ---------------- up sweep ----------------
    // i=0: res=H2 (1024), A=A2, perm=PERM2, incoming H3 (512)
    k_copy<<<(NN2 * 64) / 256, 256, 0, stream>>>(H2, UIN);
    k_scatter<<<(NN3 * 64) / 256, 256, 0, stream>>>(H3, PERM2, UIN);
    gcn(A2, NN2, UIN, upW, upb, UOUT, 1);

    // i=1: res=H1 (2048), A=A1, perm=PERM1, incoming UOUT (1024)
    k_copy<<<(NN1 * 64) / 256, 256, 0, stream>>>(H1, UIN);
    k_scatter<<<(NN2 * 64) / 256, 256, 0, stream>>>(UOUT, PERM1, UIN);
    gcn(A1, NN1, UIN, upW + 4096, upb + 64, UOUT, 1);

    // i=2: res=H0 (4096), A=adj, perm=PERM0, incoming UOUT (2048)
    k_copy<<<(NN0 * 64) / 256, 256, 0, stream>>>(H0, UIN);
    k_scatter<<<(NN1 * 64) / 256, 256, 0, stream>>>(UOUT, PERM0, UIN);
    gcn(adj, NN0, UIN, upW + 2 * 4096, upb + 2 * 64, UOUT, 0);  // no relu inside

    // final: relu + dropout(p=0) scale + linear head
    k_final<<<NN0 / 4, 256, 0, stream>>>(UOUT, prob, fcw, fcb, (float*)d_out, NN0);
}

// Round 2
// 704.608 us; speedup vs baseline: 1.5843x; 1.5843x over previous
//
#include <hip/hip_runtime.h>
#include <cstdint>
#include <cstddef>

// ---------------------------------------------------------------------------
// Graph U-Net (N=4096, F=64, DEPTH=3, ratio 0.5) forward on gfx950.
//
// Round-2 structure: topk FIRST, then compute only the pooled augmented
// adjacency  A_next = Mg @ Mg^T  (Mg = bf16(A[perm,:] + I_perm)), zero diag.
// This is 4x fewer FLOPs than dense (A+I)^2 and turns the hot kernel into an
// m97-class bf16 MFMA GEMM with global_load_lds(16B) staging.
// All topk-feeding math stays fp32 (bit-exact selections).
// ---------------------------------------------------------------------------

typedef float  f4v    __attribute__((ext_vector_type(4)));
typedef float  f32x4  __attribute__((ext_vector_type(4)));
typedef __bf16 bf16x8 __attribute__((ext_vector_type(8)));

#define NN0 4096
#define NN1 2048
#define NN2 1024
#define NN3 512

// ---------------- deg/dinv: dinv[i] = 1/sqrt(sum_j A[i,j] + 2) -------------
__global__ __launch_bounds__(256) void k_dinv(const float* __restrict__ A,
                                              float* __restrict__ dinv, int n) {
    int row = blockIdx.x;
    const float* ar = A + (size_t)row * n;
    float s = 0.f;
    for (int j = threadIdx.x; j < n; j += 256) s += ar[j];
#pragma unroll
    for (int off = 32; off > 0; off >>= 1) s += __shfl_xor(s, off);
    __shared__ float red[4];
    if ((threadIdx.x & 63) == 0) red[threadIdx.x >> 6] = s;
    __syncthreads();
    if (threadIdx.x == 0) {
        float deg = red[0] + red[1] + red[2] + red[3] + 2.0f;
        dinv[row] = (deg > 0.f) ? (1.0f / sqrtf(deg)) : 0.f;
    }
}

// ---------------- zs = dinv[i] * (X @ W), X n x 64, W 64 x 64 --------------
__global__ __launch_bounds__(256) void k_zs(const float* __restrict__ X,
                                            const float* __restrict__ W,
                                            const float* __restrict__ dinv,
                                            float* __restrict__ zs, int n) {
    __shared__ float Ws[64][65];
    __shared__ float Xs[4][64];
    int tid = threadIdx.x;
#pragma unroll
    for (int q = 0; q < 16; q++) {
        int idx = q * 256 + tid;
        Ws[idx >> 6][idx & 63] = W[idx];
    }
    int row0 = blockIdx.x << 2;
    Xs[tid >> 6][tid & 63] = X[((size_t)row0 << 6) + tid];
    __syncthreads();
    int r = tid >> 6, f = tid & 63;
    float acc = 0.f;
#pragma unroll
    for (int k = 0; k < 64; k++) acc = fmaf(Xs[r][k], Ws[k][f], acc);
    zs[((size_t)(row0 + r) << 6) + f] = dinv[row0 + r] * acc;
}

// ---------------- prop: ypart[ks] = A[64 rows, k-chunk] @ zs ---------------
// grid (n/64, 4). Deterministic split-K into 4 partial buffers.
__global__ __launch_bounds__(256) void k_prop(const float* __restrict__ A,
                                              const float* __restrict__ zs,
                                              float* __restrict__ ypart, int n) {
    int rb = blockIdx.x, ks = blockIdx.y;
    int chunk = n >> 2;
    int j0 = ks * chunk;
    __shared__ float AtT[64][68];   // transposed A tile: AtT[k][row]
    __shared__ float Zt[64][68];    // Zt[k][f]
    int tid = threadIdx.x;
    int lr = tid >> 2;              // 0..63
    int lc = (tid & 3) << 4;        // 0,16,32,48
    int ty = tid >> 4, tx = tid & 15;
    float acc[4][4] = {};
    const float* Arow = A + (size_t)(rb * 64 + lr) * n;
    for (int jt = j0; jt < j0 + chunk; jt += 64) {
#pragma unroll
        for (int q = 0; q < 4; q++) {
            f4v av = *(const f4v*)(Arow + jt + lc + (q << 2));
#pragma unroll
            for (int e = 0; e < 4; e++) AtT[lc + (q << 2) + e][lr] = av[e];
        }
#pragma unroll
        for (int q = 0; q < 4; q++) {
            f4v zv = *(const f4v*)(zs + (((size_t)(jt + lr)) << 6) + lc + (q << 2));
            *(f4v*)&Zt[lr][lc + (q << 2)] = zv;
        }
        __syncthreads();
#pragma unroll 4
        for (int k = 0; k < 64; k++) {
            f4v a4 = *(const f4v*)&AtT[k][ty << 2];
            f4v z4 = *(const f4v*)&Zt[k][tx << 2];
#pragma unroll
            for (int r = 0; r < 4; r++)
#pragma unroll
                for (int c = 0; c < 4; c++)
                    acc[r][c] = fmaf(a4[r], z4[c], acc[r][c]);
        }
        __syncthreads();
    }
    float* yp = ypart + ((size_t)ks * n << 6);
#pragma unroll
    for (int r = 0; r < 4; r++) {
        f4v o; o[0] = acc[r][0]; o[1] = acc[r][1]; o[2] = acc[r][2]; o[3] = acc[r][3];
        *(f4v*)(yp + (((size_t)(rb * 64 + (ty << 2) + r)) << 6) + (tx << 2)) = o;
    }
}

// ---------------- epilogue: H = act(dinv*(sum ypart + 2 zs) + b) -----------
__global__ __launch_bounds__(256) void k_epi(const float* __restrict__ ypart,
                                             const float* __restrict__ zs,
                                             const float* __restrict__ dinv,
                                             const float* __restrict__ b,
                                             float* __restrict__ H, int n, int relu) {
    int idx = blockIdx.x * 256 + threadIdx.x;
    int total = n << 6;
    if (idx >= total) return;
    int i = idx >> 6, f = idx & 63;
    size_t stride = (size_t)n << 6;
    float y = ypart[idx] + ypart[stride + idx] + ypart[2 * stride + idx] + ypart[3 * stride + idx];
    float v = dinv[i] * (y + 2.0f * zs[idx]) + b[f];
    if (relu) v = fmaxf(v, 0.f);
    H[idx] = v;
}

// ---------------- gather: Mg[r,:] = bf16(A[perm[r],:] + e_{perm[r]}) -------
// K = nold (power of two). Each thread converts 8 elements.
__global__ __launch_bounds__(256) void k_gather(const float* __restrict__ A,
                                                const int* __restrict__ perm,
                                                __bf16* __restrict__ Mg,
                                                int kbits3 /* log2(K)-3 */) {
    size_t idx8 = (size_t)blockIdx.x * 256 + threadIdx.x;   // index in units of 8
    int r = (int)(idx8 >> kbits3);
    int c = ((int)idx8 & ((1 << kbits3) - 1)) << 3;
    int K = 1 << (kbits3 + 3);
    int src = perm[r];
    const float* rowp = A + (size_t)src * K + c;
    f4v v0 = *(const f4v*)rowp;
    f4v v1 = *(const f4v*)(rowp + 4);
    bf16x8 t;
#pragma unroll
    for (int j = 0; j < 4; j++) {
        float v = v0[j]; if (src == c + j) v += 1.0f; t[j] = (__bf16)v;
    }
#pragma unroll
    for (int j = 0; j < 4; j++) {
        float v = v1[j]; if (src == c + 4 + j) v += 1.0f; t[4 + j] = (__bf16)v;
    }
    *(bf16x8*)(Mg + idx8 * 8) = t;
}

// ---------------- pooled aug adjacency: C = Mg @ Mg^T, zero diag -----------
// m97-class: BM=64, BN=128, BK=64, global_load_lds(16B) staging, 4 waves 2x2.
__global__ __launch_bounds__(256) void k_augmm(const __bf16* __restrict__ Mg,
                                               float* __restrict__ C,
                                               int nk, int K) {
    __shared__ __bf16 At[64 * 64];    // 8 KB, row-major, no pad (load_lds rule)
    __shared__ __bf16 Bt[128 * 64];   // 16 KB
    int tid = threadIdx.x;
    int m0 = blockIdx.x * 64, n0 = blockIdx.y * 128;
    int wave = tid >> 6, lane = tid & 63;
    int wm = (wave >> 1) << 5;        // 0 or 32
    int wn = (wave & 1) << 6;         // 0 or 64
    int quad = lane >> 4, l16 = lane & 15;
    f32x4 acc[2][4] = {};
    for (int k0 = 0; k0 < K; k0 += 64) {
#pragma unroll
        for (int it = 0; it < 2; it++) {
            int e = it * 256 + tid;
            int row = e >> 3, seg = e & 7;
            const __bf16* g = Mg + ((size_t)(m0 + row) * K + k0 + (seg << 3));
            __builtin_amdgcn_global_load_lds(
                (const __attribute__((address_space(1))) void*)g,
                (__attribute__((address_space(3))) void*)(At + (e << 3)), 16, 0, 0);
        }
#pragma unroll
        for (int it = 0; it < 4; it++) {
            int e = it * 256 + tid;
            int row = e >> 3, seg = e & 7;
            const __bf16* g = Mg + ((size_t)(n0 + row) * K + k0 + (seg << 3));
            __builtin_amdgcn_global_load_lds(
                (const __attribute__((address_space(1))) void*)g,
                (__attribute__((address_space(3))) void*)(Bt + (e << 3)), 16, 0, 0);
        }
        __syncthreads();
#pragma unroll
        for (int kk = 0; kk < 2; kk++) {
            bf16x8 af[2], bfm[4];
#pragma unroll
            for (int im = 0; im < 2; im++)
                af[im] = *(const bf16x8*)(At + ((wm + (im << 4) + l16) << 6) + (kk << 5) + (quad << 3));
#pragma unroll
            for (int in2 = 0; in2 < 4; in2++)
                bfm[in2] = *(const bf16x8*)(Bt + ((wn + (in2 << 4) + l16) << 6) + (kk << 5) + (quad << 3));
#pragma unroll
            for (int im = 0; im < 2; im++)
#pragma unroll
                for (int in2 = 0; in2 < 4; in2++)
                    acc[im][in2] = __builtin_amdgcn_mfma_f32_16x16x32_bf16(
                        af[im], bfm[in2], acc[im][in2], 0, 0, 0);
        }
        __syncthreads();
    }
    // C/D layout: col = lane&15, row = quad*4 + reg
#pragma unroll
    for (int im = 0; im < 2; im++)
#pragma unroll
        for (int in2 = 0; in2 < 4; in2++)
#pragma unroll
            for (int r = 0; r < 4; r++) {
                int grow = m0 + wm + (im << 4) + (quad << 2) + r;
                int gcol = n0 + wn + (in2 << 4) + l16;
                C[(size_t)grow * nk + gcol] = (grow == gcol) ? 0.f : acc[im][in2][r];
            }
}

// ---------------- scores: tanh((h . p)/||p||) ------------------------------
__global__ __launch_bounds__(256) void k_score(const float* __restrict__ H,
                                               const float* __restrict__ p,
                                               float* __restrict__ score, int n) {
    int wave = threadIdx.x >> 6, lane = threadIdx.x & 63;
    int row = (blockIdx.x << 2) + wave;
    float pv = p[lane];
    float hv = H[((size_t)row << 6) + lane];
    float d = hv * pv;
    float q = pv * pv;
#pragma unroll
    for (int off = 32; off > 0; off >>= 1) {
        d += __shfl_xor(d, off);
        q += __shfl_xor(q, off);
    }
    if (lane == 0) score[row] = tanhf(d / sqrtf(q));
}

// ---------------- top-k by exact rank (stable descending, jax semantics) ---
__global__ __launch_bounds__(256) void k_topk(const float* __restrict__ score,
                                              int* __restrict__ perm, int n, int k) {
    int i = blockIdx.x * 256 + threadIdx.x;
    float si = score[i];
    __shared__ float sc[256];
    int cnt = 0;
    for (int j0 = 0; j0 < n; j0 += 256) {
        sc[threadIdx.x] = score[j0 + threadIdx.x];
        __syncthreads();
#pragma unroll 8
        for (int t = 0; t < 256; t++) {
            float sj = sc[t];
            int j = j0 + t;
            cnt += ((sj > si) || (sj == si && j < i)) ? 1 : 0;
        }
        __syncthreads();
    }
    if (cnt < k) perm[cnt] = i;
}

// ---------------- pooled features: HP[r] = H[perm[r]] * score[perm[r]] -----
__global__ __launch_bounds__(256) void k_poolx(const float* __restrict__ H,
                                               const float* __restrict__ score,
                                               const int* __restrict__ perm,
                                               float* __restrict__ HP) {
    int idx = blockIdx.x * 256 + threadIdx.x;
    int r = idx >> 6, f = idx & 63;
    int src = perm[r];
    HP[idx] = H[((size_t)src << 6) + f] * score[src];
}

// ---------------- copy / scatter-add (unpool) ------------------------------
__global__ __launch_bounds__(256) void k_copy(const float* __restrict__ s,
                                              float* __restrict__ d) {
    int idx = blockIdx.x * 256 + threadIdx.x;
    d[idx] = s[idx];
}
__global__ __launch_bounds__(256) void k_scatter(const float* __restrict__ hs,
                                                 const int* __restrict__ perm,
                                                 float* __restrict__ buf) {
    int idx = blockIdx.x * 256 + threadIdx.x;
    int r = idx >> 6, f = idx & 63;
    buf[((size_t)perm[r] << 6) + f] += hs[idx];   // perm rows unique: no atomics
}

// ---------------- final: out = relu(h)/(1-prob) @ fc_w + fc_b --------------
__global__ __launch_bounds__(256) void k_final(const float* __restrict__ H,
                                               const float* __restrict__ prob,
                                               const float* __restrict__ fcw,
                                               const float* __restrict__ fcb,
                                               float* __restrict__ out, int n) {
    int wave = threadIdx.x >> 6, lane = threadIdx.x & 63;
    int row = (blockIdx.x << 2) + wave;
    float scale = 1.0f / (1.0f - prob[0]);
    float h = fmaxf(H[((size_t)row << 6) + lane], 0.f);
    float v = h * fcw[lane];
#pragma unroll
    for (int off = 32; off > 0; off >>= 1) v += __shfl_xor(v, off);
    if (lane == 0) out[row] = v * scale + fcb[0];
}

// ===========================================================================
extern "C" void kernel_launch(void* const* d_in, const int* in_sizes, int n_in,
                              void* d_out, int out_size, void* d_ws, size_t ws_size,
                              hipStream_t stream) {
    (void)in_sizes; (void)n_in; (void)out_size;
    const float* x     = (const float*)d_in[0];
    const float* adj   = (const float*)d_in[1];
    const float* prob  = (const float*)d_in[2];
    const float* downW = (const float*)d_in[3];   // 4 x 64 x 64
    const float* downb = (const float*)d_in[4];   // 4 x 64
    const float* poolw = (const float*)d_in[5];   // 3 x 64
    const float* upW   = (const float*)d_in[6];   // 3 x 64 x 64
    const float* upb   = (const float*)d_in[7];   // 3 x 64
    const float* fcw   = (const float*)d_in[8];   // 64
    const float* fcb   = (const float*)d_in[9];   // 1

    char* ws = (char*)d_ws;
    // workspace layout (bytes)
    __bf16* MG   = (__bf16*)(ws + 0);           // 16 MB (2048 x 4096 bf16 max)
    float* A1    = (float*)(ws + 16777216);     // 16 MB
    float* A2    = (float*)(ws + 33554432);     // 4 MB
    float* A3    = (float*)(ws + 37748736);     // 1 MB
    float* H0    = (float*)(ws + 38797312);     // 1 MB
    float* H1    = (float*)(ws + 39845888);     // 512 KB
    float* H2    = (float*)(ws + 40370176);     // 256 KB
    float* H3    = (float*)(ws + 40632320);     // 128 KB
    float* HP    = (float*)(ws + 40763392);     // 512 KB
    float* ZS    = (float*)(ws + 41287680);     // 1 MB
    float* YP    = (float*)(ws + 42336256);     // 4 MB (4-way split-K partials)
    float* UIN   = (float*)(ws + 46530560);     // 1 MB
    float* UOUT  = (float*)(ws + 47579136);     // 1 MB
    float* DINV0 = (float*)(ws + 48627712);     // 16 KB
    float* DINV1 = (float*)(ws + 48644096);     // 8 KB
    float* DINV2 = (float*)(ws + 48652288);     // 4 KB
    float* DINV3 = (float*)(ws + 48656384);     // 2 KB
    float* SCORE = (float*)(ws + 48658432);     // 16 KB
    int*   PERM0 = (int*)(ws + 48674816);       // 8 KB
    int*   PERM1 = (int*)(ws + 48683008);       // 4 KB
    int*   PERM2 = (int*)(ws + 48687104);       // 2 KB
    if (ws_size < (size_t)48689152) return;     // insufficient scratch: bail loudly

    auto gcn = [&](const float* A, const float* dinv, int n, const float* Xin,
                   const float* W, const float* b, float* Hout, int relu) {
        k_zs<<<n / 4, 256, 0, stream>>>(Xin, W, dinv, ZS, n);
        k_prop<<<dim3(n / 64, 4), 256, 0, stream>>>(A, ZS, YP, n);
        k_epi<<<(n * 64) / 256, 256, 0, stream>>>(YP, ZS, dinv, b, Hout, n, relu);
    };

    // ---------------- down sweep ----------------
    k_dinv<<<NN0, 256, 0, stream>>>(adj, DINV0, NN0);
    gcn(adj, DINV0, NN0, x, downW, downb, H0, 1);

    // level 0 -> 1: topk first, then pooled augment A1 = Mg@Mg^T
    k_score<<<NN0 / 4, 256, 0, stream>>>(H0, poolw + 0, SCORE, NN0);
    k_topk<<<NN0 / 256, 256, 0, stream>>>(SCORE, PERM0, NN0, NN1);
    k_gather<<<(NN1 * NN0 / 8) / 256, 256, 0, stream>>>(adj, PERM0, MG, 9);
    k_augmm<<<dim3(NN1 / 64, NN1 / 128), 256, 0, stream>>>(MG, A1, NN1, NN0);
    k_poolx<<<(NN1 * 64) / 256, 256, 0, stream>>>(H0, SCORE, PERM0, HP);
    k_dinv<<<NN1, 256, 0, stream>>>(A1, DINV1, NN1);
    gcn(A1, DINV1, NN1, HP, downW + 4096, downb + 64, H1, 1);

    // level 1 -> 2
    k_score<<<NN1 / 4, 256, 0, stream>>>(H1, poolw + 64, SCORE, NN1);
    k_topk<<<NN1 / 256, 256, 0, stream>>>(SCORE, PERM1, NN1, NN2);
    k_gather<<<(NN2 * NN1 / 8) / 256, 256, 0, stream>>>(A1, PERM1, MG, 8);
    k_augmm<<<dim3(NN2 / 64, NN2 / 128), 256, 0, stream>>>(MG, A2, NN2, NN1);
    k_poolx<<<(NN2 * 64) / 256, 256, 0, stream>>>(H1, SCORE, PERM1, HP);
    k_dinv<<<NN2, 256, 0, stream>>>(A2, DINV2, NN2);
    gcn(A2, DINV2, NN2, HP, downW + 2 * 4096, downb + 2 * 64, H2, 1);

    // level 2 -> 3
    k_score<<<NN2 / 4, 256, 0, stream>>>(H2, poolw + 128, SCORE, NN2);
    k_topk<<<NN2 / 256, 256, 0, stream>>>(SCORE, PERM2, NN2, NN3);
    k_gather<<<(NN3 * NN2 / 8) / 256, 256, 0, stream>>>(A2, PERM2, MG, 7);
    k_augmm<<<dim3(NN3 / 64, NN3 / 128), 256, 0, stream>>>(MG, A3, NN3, NN2);
    k_poolx<<<(NN3 * 64) / 256, 256, 0, stream>>>(H2, SCORE, PERM2, HP);
    k_dinv<<<NN3, 256, 0, stream>>>(A3, DINV3, NN3);
    gcn(A3, DINV3, NN3, HP, downW + 3 * 4096, downb + 3 * 64, H3, 1);

    // ---------------- up sweep ----------------
    // i=0: res=H2 (1024), A=A2, perm=PERM2, incoming H3 (512)
    k_copy<<<(NN2 * 64) / 256, 256, 0, stream>>>(H2, UIN);
    k_scatter<<<(NN3 * 64) / 256, 256, 0, stream>>>(H3, PERM2, UIN);
    gcn(A2, DINV2, NN2, UIN, upW, upb, UOUT, 1);

    // i=1: res=H1 (2048), A=A1, perm=PERM1, incoming UOUT (1024)
    k_copy<<<(NN1 * 64) / 256, 256, 0, stream>>>(H1, UIN);
    k_scatter<<<(NN2 * 64) / 256, 256, 0, stream>>>(UOUT, PERM1, UIN);
    gcn(A1, DINV1, NN1, UIN, upW + 4096, upb + 64, UOUT, 1);

    // i=2: res=H0 (4096), A=adj, perm=PERM0, incoming UOUT (2048)
    k_copy<<<(NN0 * 64) / 256, 256, 0, stream>>>(H0, UIN);
    k_scatter<<<(NN1 * 64) / 256, 256, 0, stream>>>(UOUT, PERM0, UIN);
    gcn(adj, DINV0, NN0, UIN, upW + 2 * 4096, upb + 2 * 64, UOUT, 0);  // no relu

    // final: relu + dropout(p=0) scale + linear head
    k_final<<<NN0 / 4, 256, 0, stream>>>(UOUT, prob, fcw, fcb, (float*)d_out, NN0);
}

// Round 3
// 557.465 us; speedup vs baseline: 2.0025x; 1.2640x over previous
//
#include <hip/hip_runtime.h>
#include <cstdint>
#include <cstddef>

// ---------------------------------------------------------------------------
// Graph U-Net (N=4096, F=64, DEPTH=3, ratio 0.5) forward on gfx950.
//
// Round-3: parallel top-k. Rank counting distributed over (i,j) 256x256
// chunk pairs with deterministic integer atomicAdd partial sums (was: 16
// workgroups serially scanning all scores -> 104 us, 0.7% occupancy).
// ---------------------------------------------------------------------------

typedef float  f4v    __attribute__((ext_vector_type(4)));
typedef float  f32x4  __attribute__((ext_vector_type(4)));
typedef __bf16 bf16x8 __attribute__((ext_vector_type(8)));

#define NN0 4096
#define NN1 2048
#define NN2 1024
#define NN3 512

// ---------------- deg/dinv: dinv[i] = 1/sqrt(sum_j A[i,j] + 2) -------------
__global__ __launch_bounds__(256) void k_dinv(const float* __restrict__ A,
                                              float* __restrict__ dinv, int n) {
    int row = blockIdx.x;
    const float* ar = A + (size_t)row * n;
    float s = 0.f;
    for (int j = threadIdx.x; j < n; j += 256) s += ar[j];
#pragma unroll
    for (int off = 32; off > 0; off >>= 1) s += __shfl_xor(s, off);
    __shared__ float red[4];
    if ((threadIdx.x & 63) == 0) red[threadIdx.x >> 6] = s;
    __syncthreads();
    if (threadIdx.x == 0) {
        float deg = red[0] + red[1] + red[2] + red[3] + 2.0f;
        dinv[row] = (deg > 0.f) ? (1.0f / sqrtf(deg)) : 0.f;
    }
}

// ---------------- zs = dinv[i] * (X @ W), X n x 64, W 64 x 64 --------------
__global__ __launch_bounds__(256) void k_zs(const float* __restrict__ X,
                                            const float* __restrict__ W,
                                            const float* __restrict__ dinv,
                                            float* __restrict__ zs, int n) {
    __shared__ float Ws[64][65];
    __shared__ float Xs[4][64];
    int tid = threadIdx.x;
#pragma unroll
    for (int q = 0; q < 16; q++) {
        int idx = q * 256 + tid;
        Ws[idx >> 6][idx & 63] = W[idx];
    }
    int row0 = blockIdx.x << 2;
    Xs[tid >> 6][tid & 63] = X[((size_t)row0 << 6) + tid];
    __syncthreads();
    int r = tid >> 6, f = tid & 63;
    float acc = 0.f;
#pragma unroll
    for (int k = 0; k < 64; k++) acc = fmaf(Xs[r][k], Ws[k][f], acc);
    zs[((size_t)(row0 + r) << 6) + f] = dinv[row0 + r] * acc;
}

// ---------------- prop: ypart[ks] = A[64 rows, k-chunk] @ zs ---------------
// grid (n/64, 4). Deterministic split-K into 4 partial buffers.
__global__ __launch_bounds__(256) void k_prop(const float* __restrict__ A,
                                              const float* __restrict__ zs,
                                              float* __restrict__ ypart, int n) {
    int rb = blockIdx.x, ks = blockIdx.y;
    int chunk = n >> 2;
    int j0 = ks * chunk;
    __shared__ float AtT[64][68];   // transposed A tile: AtT[k][row]
    __shared__ float Zt[64][68];    // Zt[k][f]
    int tid = threadIdx.x;
    int lr = tid >> 2;              // 0..63
    int lc = (tid & 3) << 4;        // 0,16,32,48
    int ty = tid >> 4, tx = tid & 15;
    float acc[4][4] = {};
    const float* Arow = A + (size_t)(rb * 64 + lr) * n;
    for (int jt = j0; jt < j0 + chunk; jt += 64) {
#pragma unroll
        for (int q = 0; q < 4; q++) {
            f4v av = *(const f4v*)(Arow + jt + lc + (q << 2));
#pragma unroll
            for (int e = 0; e < 4; e++) AtT[lc + (q << 2) + e][lr] = av[e];
        }
#pragma unroll
        for (int q = 0; q < 4; q++) {
            f4v zv = *(const f4v*)(zs + (((size_t)(jt + lr)) << 6) + lc + (q << 2));
            *(f4v*)&Zt[lr][lc + (q << 2)] = zv;
        }
        __syncthreads();
#pragma unroll 4
        for (int k = 0; k < 64; k++) {
            f4v a4 = *(const f4v*)&AtT[k][ty << 2];
            f4v z4 = *(const f4v*)&Zt[k][tx << 2];
#pragma unroll
            for (int r = 0; r < 4; r++)
#pragma unroll
                for (int c = 0; c < 4; c++)
                    acc[r][c] = fmaf(a4[r], z4[c], acc[r][c]);
        }
        __syncthreads();
    }
    float* yp = ypart + ((size_t)ks * n << 6);
#pragma unroll
    for (int r = 0; r < 4; r++) {
        f4v o; o[0] = acc[r][0]; o[1] = acc[r][1]; o[2] = acc[r][2]; o[3] = acc[r][3];
        *(f4v*)(yp + (((size_t)(rb * 64 + (ty << 2) + r)) << 6) + (tx << 2)) = o;
    }
}

// ---------------- epilogue: H = act(dinv*(sum ypart + 2 zs) + b) -----------
__global__ __launch_bounds__(256) void k_epi(const float* __restrict__ ypart,
                                             const float* __restrict__ zs,
                                             const float* __restrict__ dinv,
                                             const float* __restrict__ b,
                                             float* __restrict__ H, int n, int relu) {
    int idx = blockIdx.x * 256 + threadIdx.x;
    int total = n << 6;
    if (idx >= total) return;
    int i = idx >> 6, f = idx & 63;
    size_t stride = (size_t)n << 6;
    float y = ypart[idx] + ypart[stride + idx] + ypart[2 * stride + idx] + ypart[3 * stride + idx];
    float v = dinv[i] * (y + 2.0f * zs[idx]) + b[f];
    if (relu) v = fmaxf(v, 0.f);
    H[idx] = v;
}

// ---------------- gather: Mg[r,:] = bf16(A[perm[r],:] + e_{perm[r]}) -------
// K = nold (power of two). Each thread converts 8 elements.
__global__ __launch_bounds__(256) void k_gather(const float* __restrict__ A,
                                                const int* __restrict__ perm,
                                                __bf16* __restrict__ Mg,
                                                int kbits3 /* log2(K)-3 */) {
    size_t idx8 = (size_t)blockIdx.x * 256 + threadIdx.x;   // index in units of 8
    int r = (int)(idx8 >> kbits3);
    int c = ((int)idx8 & ((1 << kbits3) - 1)) << 3;
    int K = 1 << (kbits3 + 3);
    int src = perm[r];
    const float* rowp = A + (size_t)src * K + c;
    f4v v0 = *(const f4v*)rowp;
    f4v v1 = *(const f4v*)(rowp + 4);
    bf16x8 t;
#pragma unroll
    for (int j = 0; j < 4; j++) {
        float v = v0[j]; if (src == c + j) v += 1.0f; t[j] = (__bf16)v;
    }
#pragma unroll
    for (int j = 0; j < 4; j++) {
        float v = v1[j]; if (src == c + 4 + j) v += 1.0f; t[4 + j] = (__bf16)v;
    }
    *(bf16x8*)(Mg + idx8 * 8) = t;
}

// ---------------- pooled aug adjacency: C = Mg @ Mg^T, zero diag -----------
// m97-class: BM=64, BN=128, BK=64, global_load_lds(16B) staging, 4 waves 2x2.
__global__ __launch_bounds__(256) void k_augmm(const __bf16* __restrict__ Mg,
                                               float* __restrict__ C,
                                               int nk, int K) {
    __shared__ __bf16 At[64 * 64];    // 8 KB, row-major, no pad (load_lds rule)
    __shared__ __bf16 Bt[128 * 64];   // 16 KB
    int tid = threadIdx.x;
    int m0 = blockIdx.x * 64, n0 = blockIdx.y * 128;
    int wave = tid >> 6, lane = tid & 63;
    int wm = (wave >> 1) << 5;        // 0 or 32
    int wn = (wave & 1) << 6;         // 0 or 64
    int quad = lane >> 4, l16 = lane & 15;
    f32x4 acc[2][4] = {};
    for (int k0 = 0; k0 < K; k0 += 64) {
#pragma unroll
        for (int it = 0; it < 2; it++) {
            int e = it * 256 + tid;
            int row = e >> 3, seg = e & 7;
            const __bf16* g = Mg + ((size_t)(m0 + row) * K + k0 + (seg << 3));
            __builtin_amdgcn_global_load_lds(
                (const __attribute__((address_space(1))) void*)g,
                (__attribute__((address_space(3))) void*)(At + (e << 3)), 16, 0, 0);
        }
#pragma unroll
        for (int it = 0; it < 4; it++) {
            int e = it * 256 + tid;
            int row = e >> 3, seg = e & 7;
            const __bf16* g = Mg + ((size_t)(n0 + row) * K + k0 + (seg << 3));
            __builtin_amdgcn_global_load_lds(
                (const __attribute__((address_space(1))) void*)g,
                (__attribute__((address_space(3))) void*)(Bt + (e << 3)), 16, 0, 0);
        }
        __syncthreads();
#pragma unroll
        for (int kk = 0; kk < 2; kk++) {
            bf16x8 af[2], bfm[4];
#pragma unroll
            for (int im = 0; im < 2; im++)
                af[im] = *(const bf16x8*)(At + ((wm + (im << 4) + l16) << 6) + (kk << 5) + (quad << 3));
#pragma unroll
            for (int in2 = 0; in2 < 4; in2++)
                bfm[in2] = *(const bf16x8*)(Bt + ((wn + (in2 << 4) + l16) << 6) + (kk << 5) + (quad << 3));
#pragma unroll
            for (int im = 0; im < 2; im++)
#pragma unroll
                for (int in2 = 0; in2 < 4; in2++)
                    acc[im][in2] = __builtin_amdgcn_mfma_f32_16x16x32_bf16(
                        af[im], bfm[in2], acc[im][in2], 0, 0, 0);
        }
        __syncthreads();
    }
    // C/D layout: col = lane&15, row = quad*4 + reg
#pragma unroll
    for (int im = 0; im < 2; im++)
#pragma unroll
        for (int in2 = 0; in2 < 4; in2++)
#pragma unroll
            for (int r = 0; r < 4; r++) {
                int grow = m0 + wm + (im << 4) + (quad << 2) + r;
                int gcol = n0 + wn + (in2 << 4) + l16;
                C[(size_t)grow * nk + gcol] = (grow == gcol) ? 0.f : acc[im][in2][r];
            }
}

// ---------------- scores: tanh((h . p)/||p||) ------------------------------
__global__ __launch_bounds__(256) void k_score(const float* __restrict__ H,
                                               const float* __restrict__ p,
                                               float* __restrict__ score, int n) {
    int wave = threadIdx.x >> 6, lane = threadIdx.x & 63;
    int row = (blockIdx.x << 2) + wave;
    float pv = p[lane];
    float hv = H[((size_t)row << 6) + lane];
    float d = hv * pv;
    float q = pv * pv;
#pragma unroll
    for (int off = 32; off > 0; off >>= 1) {
        d += __shfl_xor(d, off);
        q += __shfl_xor(q, off);
    }
    if (lane == 0) score[row] = tanhf(d / sqrtf(q));
}

// ---------------- parallel top-k --------------------------------------------
__global__ __launch_bounds__(256) void k_zeroi(int* __restrict__ p) {
    p[blockIdx.x * 256 + threadIdx.x] = 0;
}
// grid (n/256, n/256): block (bx,by) ranks i-chunk bx against j-chunk by.
// Integer atomicAdd partial sums are associative -> deterministic.
__global__ __launch_bounds__(256) void k_topk_count(const float* __restrict__ score,
                                                    int* __restrict__ cnt, int n) {
    __shared__ float sc[256];
    int j0 = blockIdx.y * 256;
    sc[threadIdx.x] = score[j0 + threadIdx.x];
    int i = blockIdx.x * 256 + threadIdx.x;
    float si = score[i];
    __syncthreads();
    int c = 0;
#pragma unroll 8
    for (int t = 0; t < 256; t++) {
        float sj = sc[t];
        int j = j0 + t;
        c += ((sj > si) || (sj == si && j < i)) ? 1 : 0;
    }
    atomicAdd(&cnt[i], c);
}
// rank < k  ->  perm[rank] = i   (exact jax stable-descending order)
__global__ __launch_bounds__(256) void k_topk_scatter(const int* __restrict__ cnt,
                                                      int* __restrict__ perm, int k) {
    int i = blockIdx.x * 256 + threadIdx.x;
    int c = cnt[i];
    if (c < k) perm[c] = i;
}

// ---------------- pooled features: HP[r] = H[perm[r]] * score[perm[r]] -----
__global__ __launch_bounds__(256) void k_poolx(const float* __restrict__ H,
                                               const float* __restrict__ score,
                                               const int* __restrict__ perm,
                                               float* __restrict__ HP) {
    int idx = blockIdx.x * 256 + threadIdx.x;
    int r = idx >> 6, f = idx & 63;
    int src = perm[r];
    HP[idx] = H[((size_t)src << 6) + f] * score[src];
}

// ---------------- copy / scatter-add (unpool) ------------------------------
__global__ __launch_bounds__(256) void k_copy(const float* __restrict__ s,
                                              float* __restrict__ d) {
    int idx = blockIdx.x * 256 + threadIdx.x;
    d[idx] = s[idx];
}
__global__ __launch_bounds__(256) void k_scatter(const float* __restrict__ hs,
                                                 const int* __restrict__ perm,
                                                 float* __restrict__ buf) {
    int idx = blockIdx.x * 256 + threadIdx.x;
    int r = idx >> 6, f = idx & 63;
    buf[((size_t)perm[r] << 6) + f] += hs[idx];   // perm rows unique: no atomics
}

// ---------------- final: out = relu(h)/(1-prob) @ fc_w + fc_b --------------
__global__ __launch_bounds__(256) void k_final(const float* __restrict__ H,
                                               const float* __restrict__ prob,
                                               const float* __restrict__ fcw,
                                               const float* __restrict__ fcb,
                                               float* __restrict__ out, int n) {
    int wave = threadIdx.x >> 6, lane = threadIdx.x & 63;
    int row = (blockIdx.x << 2) + wave;
    float scale = 1.0f / (1.0f - prob[0]);
    float h = fmaxf(H[((size_t)row << 6) + lane], 0.f);
    float v = h * fcw[lane];
#pragma unroll
    for (int off = 32; off > 0; off >>= 1) v += __shfl_xor(v, off);
    if (lane == 0) out[row] = v * scale + fcb[0];
}

// ===========================================================================
extern "C" void kernel_launch(void* const* d_in, const int* in_sizes, int n_in,
                              void* d_out, int out_size, void* d_ws, size_t ws_size,
                              hipStream_t stream) {
    (void)in_sizes; (void)n_in; (void)out_size;
    const float* x     = (const float*)d_in[0];
    const float* adj   = (const float*)d_in[1];
    const float* prob  = (const float*)d_in[2];
    const float* downW = (const float*)d_in[3];   // 4 x 64 x 64
    const float* downb = (const float*)d_in[4];   // 4 x 64
    const float* poolw = (const float*)d_in[5];   // 3 x 64
    const float* upW   = (const float*)d_in[6];   // 3 x 64 x 64
    const float* upb   = (const float*)d_in[7];   // 3 x 64
    const float* fcw   = (const float*)d_in[8];   // 64
    const float* fcb   = (const float*)d_in[9];   // 1

    char* ws = (char*)d_ws;
    // workspace layout (bytes)
    __bf16* MG   = (__bf16*)(ws + 0);           // 16 MB (2048 x 4096 bf16 max)
    float* A1    = (float*)(ws + 16777216);     // 16 MB
    float* A2    = (float*)(ws + 33554432);     // 4 MB
    float* A3    = (float*)(ws + 37748736);     // 1 MB
    float* H0    = (float*)(ws + 38797312);     // 1 MB
    float* H1    = (float*)(ws + 39845888);     // 512 KB
    float* H2    = (float*)(ws + 40370176);     // 256 KB
    float* H3    = (float*)(ws + 40632320);     // 128 KB
    float* HP    = (float*)(ws + 40763392);     // 512 KB
    float* ZS    = (float*)(ws + 41287680);     // 1 MB
    float* YP    = (float*)(ws + 42336256);     // 4 MB (4-way split-K partials)
    float* UIN   = (float*)(ws + 46530560);     // 1 MB
    float* UOUT  = (float*)(ws + 47579136);     // 1 MB
    float* DINV0 = (float*)(ws + 48627712);     // 16 KB
    float* DINV1 = (float*)(ws + 48644096);     // 8 KB
    float* DINV2 = (float*)(ws + 48652288);     // 4 KB
    float* DINV3 = (float*)(ws + 48656384);     // 2 KB
    float* SCORE = (float*)(ws + 48658432);     // 16 KB
    int*   PERM0 = (int*)(ws + 48674816);       // 8 KB
    int*   PERM1 = (int*)(ws + 48683008);       // 4 KB
    int*   PERM2 = (int*)(ws + 48687104);       // 2 KB
    int*   CNT   = (int*)(ws + 48689152);       // 16 KB
    if (ws_size < (size_t)48705536) return;     // insufficient scratch: bail loudly

    auto gcn = [&](const float* A, const float* dinv, int n, const float* Xin,
                   const float* W, const float* b, float* Hout, int relu) {
        k_zs<<<n / 4, 256, 0, stream>>>(Xin, W, dinv, ZS, n);
        k_prop<<<dim3(n / 64, 4), 256, 0, stream>>>(A, ZS, YP, n);
        k_epi<<<(n * 64) / 256, 256, 0, stream>>>(YP, ZS, dinv, b, Hout, n, relu);
    };
    auto topk = [&](int n, int k, int* perm) {
        k_zeroi<<<n / 256, 256, 0, stream>>>(CNT);
        k_topk_count<<<dim3(n / 256, n / 256), 256, 0, stream>>>(SCORE, CNT, n);
        k_topk_scatter<<<n / 256, 256, 0, stream>>>(CNT, perm, k);
    };

    // ---------------- down sweep ----------------
    k_dinv<<<NN0, 256, 0, stream>>>(adj, DINV0, NN0);
    gcn(adj, DINV0, NN0, x, downW, downb, H0, 1);

    // level 0 -> 1: topk first, then pooled augment A1 = Mg@Mg^T
    k_score<<<NN0 / 4, 256, 0, stream>>>(H0, poolw + 0, SCORE, NN0);
    topk(NN0, NN1, PERM0);
    k_gather<<<(NN1 * NN0 / 8) / 256, 256, 0, stream>>>(adj, PERM0, MG, 9);
    k_augmm<<<dim3(NN1 / 64, NN1 / 128), 256, 0, stream>>>(MG, A1, NN1, NN0);
    k_poolx<<<(NN1 * 64) / 256, 256, 0, stream>>>(H0, SCORE, PERM0, HP);
    k_dinv<<<NN1, 256, 0, stream>>>(A1, DINV1, NN1);
    gcn(A1, DINV1, NN1, HP, downW + 4096, downb + 64, H1, 1);

    // level 1 -> 2
    k_score<<<NN1 / 4, 256, 0, stream>>>(H1, poolw + 64, SCORE, NN1);
    topk(NN1, NN2, PERM1);
    k_gather<<<(NN2 * NN1 / 8) / 256, 256, 0, stream>>>(A1, PERM1, MG, 8);
    k_augmm<<<dim3(NN2 / 64, NN2 / 128), 256, 0, stream>>>(MG, A2, NN2, NN1);
    k_poolx<<<(NN2 * 64) / 256, 256, 0, stream>>>(H1, SCORE, PERM1, HP);
    k_dinv<<<NN2, 256, 0, stream>>>(A2, DINV2, NN2);
    gcn(A2, DINV2, NN2, HP, downW + 2 * 4096, downb + 2 * 64, H2, 1);

    // level 2 -> 3
    k_score<<<NN2 / 4, 256, 0, stream>>>(H2, poolw + 128, SCORE, NN2);
    topk(NN2, NN3, PERM2);
    k_gather<<<(NN3 * NN2 / 8) / 256, 256, 0, stream>>>(A2, PERM2, MG, 7);
    k_augmm<<<dim3(NN3 / 64, NN3 / 128), 256, 0, stream>>>(MG, A3, NN3, NN2);
    k_poolx<<<(NN3 * 64) / 256, 256, 0, stream>>>(H2, SCORE, PERM2, HP);
    k_dinv<<<NN3, 256, 0, stream>>>(A3, DINV3, NN3);
    gcn(A3, DINV3, NN3, HP, downW + 3 * 4096, downb + 3 * 64, H3, 1);

    // ---------------- up sweep ----------------
    // i=0: res=H2 (1024), A=A2, perm=PERM2, incoming H3 (512)
    k_copy<<<(NN2 * 64) / 256, 256, 0, stream>>>(H2, UIN);
    k_scatter<<<(NN3 * 64) / 256, 256, 0, stream>>>(H3, PERM2, UIN);
    gcn(A2, DINV2, NN2, UIN, upW, upb, UOUT, 1);

    // i=1: res=H1 (2048), A=A1, perm=PERM1, incoming UOUT (1024)
    k_copy<<<(NN1 * 64) / 256, 256, 0, stream>>>(H1, UIN);
    k_scatter<<<(NN2 * 64) / 256, 256, 0, stream>>>(UOUT, PERM1, UIN);
    gcn(A1, DINV1, NN1, UIN, upW + 4096, upb + 64, UOUT, 1);

    // i=2: res=H0 (4096), A=adj, perm=PERM0, incoming UOUT (2048)
    k_copy<<<(NN0 * 64) / 256, 256, 0, stream>>>(H0, UIN);
    k_scatter<<<(NN1 * 64) / 256, 256, 0, stream>>>(UOUT, PERM0, UIN);
    gcn(adj, DINV0, NN0, UIN, upW + 2 * 4096, upb + 2 * 64, UOUT, 0);  // no relu

    // final: relu + dropout(p=0) scale + linear head
    k_final<<<NN0 / 4, 256, 0, stream>>>(UOUT, prob, fcw, fcb, (float*)d_out, NN0);
}

// Round 4
// 490.717 us; speedup vs baseline: 2.2749x; 1.1360x over previous
//
#include <hip/hip_runtime.h>
#include <cstdint>
#include <cstddef>

// ---------------------------------------------------------------------------
// Graph U-Net (N=4096, F=64, DEPTH=3, ratio 0.5) forward on gfx950.
//
// Round-4:
//  * k_augmm: XOR-swizzled LDS (kills 16-way bank conflicts: row stride was
//    exactly 32 banks), BN=64 variant for small levels (grid >= 256 blocks),
//    DEG row-sums fused into epilogue as exact-integer fp32 atomics.
//  * Fusions: score+CNT-zero into k_epi; poolx into k_zs_pool; unpool into
//    k_zs_unpool (inverse perm from k_topk_scatter). 53 -> 35 graph nodes.
//  * All topk-feeding math bitwise-identical to previous passing rounds.
// ---------------------------------------------------------------------------

typedef float  f4v    __attribute__((ext_vector_type(4)));
typedef float  f32x4  __attribute__((ext_vector_type(4)));
typedef __bf16 bf16x8 __attribute__((ext_vector_type(8)));

#define NN0 4096
#define NN1 2048
#define NN2 1024
#define NN3 512

// ---------------- rowsum: deg[i] = sum_j A[i,j]  (integers, exact) ---------
__global__ __launch_bounds__(256) void k_rowsum(const float* __restrict__ A,
                                                float* __restrict__ deg, int n) {
    int row = blockIdx.x;
    const float* ar = A + (size_t)row * n;
    float s = 0.f;
    for (int j = threadIdx.x; j < n; j += 256) s += ar[j];
#pragma unroll
    for (int off = 32; off > 0; off >>= 1) s += __shfl_xor(s, off);
    __shared__ float red[4];
    if ((threadIdx.x & 63) == 0) red[threadIdx.x >> 6] = s;
    __syncthreads();
    if (threadIdx.x == 0) deg[row] = red[0] + red[1] + red[2] + red[3];
}

// ---------------- zs = dinv[i] * (X @ W)  (3 input variants) ---------------
// dinv recomputed as 1/sqrt(deg+2) (bitwise-identical to previous rounds).
__global__ __launch_bounds__(256) void k_zs(const float* __restrict__ X,
                                            const float* __restrict__ W,
                                            const float* __restrict__ deg,
                                            float* __restrict__ zs, int n) {
    __shared__ float Ws[64][65];
    __shared__ float Xs[4][64];
    int tid = threadIdx.x;
#pragma unroll
    for (int q = 0; q < 16; q++) {
        int idx = q * 256 + tid;
        Ws[idx >> 6][idx & 63] = W[idx];
    }
    int row0 = blockIdx.x << 2;
    Xs[tid >> 6][tid & 63] = X[((size_t)row0 << 6) + tid];
    __syncthreads();
    int r = tid >> 6, f = tid & 63;
    float acc = 0.f;
#pragma unroll
    for (int k = 0; k < 64; k++) acc = fmaf(Xs[r][k], Ws[k][f], acc);
    float di = 1.0f / sqrtf(deg[row0 + r] + 2.0f);
    zs[((size_t)(row0 + r) << 6) + f] = di * acc;
}

// down-level input: X_eff[r] = H[perm[r]] * score[perm[r]]
__global__ __launch_bounds__(256) void k_zs_pool(const float* __restrict__ H,
                                                 const float* __restrict__ sc,
                                                 const int* __restrict__ perm,
                                                 const float* __restrict__ W,
                                                 const float* __restrict__ deg,
                                                 float* __restrict__ zs) {
    __shared__ float Ws[64][65];
    __shared__ float Xs[4][64];
    int tid = threadIdx.x;
#pragma unroll
    for (int q = 0; q < 16; q++) {
        int idx = q * 256 + tid;
        Ws[idx >> 6][idx & 63] = W[idx];
    }
    int row0 = blockIdx.x << 2;
    int r = tid >> 6, f = tid & 63;
    int src = perm[row0 + r];
    Xs[r][f] = H[((size_t)src << 6) + f] * sc[src];
    __syncthreads();
    float acc = 0.f;
#pragma unroll
    for (int k = 0; k < 64; k++) acc = fmaf(Xs[r][k], Ws[k][f], acc);
    float di = 1.0f / sqrtf(deg[row0 + r] + 2.0f);
    zs[((size_t)(row0 + r) << 6) + f] = di * acc;
}

// up-level input: X_eff[i] = RES[i] + (inv[i]>=0 ? HS[inv[i]] : 0)
__global__ __launch_bounds__(256) void k_zs_unpool(const float* __restrict__ RES,
                                                   const float* __restrict__ HS,
                                                   const int* __restrict__ inv,
                                                   const float* __restrict__ W,
                                                   const float* __restrict__ deg,
                                                   float* __restrict__ zs) {
    __shared__ float Ws[64][65];
    __shared__ float Xs[4][64];
    int tid = threadIdx.x;
#pragma unroll
    for (int q = 0; q < 16; q++) {
        int idx = q * 256 + tid;
        Ws[idx >> 6][idx & 63] = W[idx];
    }
    int row0 = blockIdx.x << 2;
    int r = tid >> 6, f = tid & 63;
    int grow = row0 + r;
    int iv = inv[grow];
    float xv = RES[((size_t)grow << 6) + f];
    if (iv >= 0) xv += HS[((size_t)iv << 6) + f];
    Xs[r][f] = xv;
    __syncthreads();
    float acc = 0.f;
#pragma unroll
    for (int k = 0; k < 64; k++) acc = fmaf(Xs[r][k], Ws[k][f], acc);
    float di = 1.0f / sqrtf(deg[grow] + 2.0f);
    zs[((size_t)grow << 6) + f] = di * acc;
}

// ---------------- prop: ypart[ks] = A[64 rows, k-chunk] @ zs ---------------
__global__ __launch_bounds__(256) void k_prop(const float* __restrict__ A,
                                              const float* __restrict__ zs,
                                              float* __restrict__ ypart, int n) {
    int rb = blockIdx.x, ks = blockIdx.y;
    int chunk = n >> 2;
    int j0 = ks * chunk;
    __shared__ float AtT[64][68];
    __shared__ float Zt[64][68];
    int tid = threadIdx.x;
    int lr = tid >> 2;
    int lc = (tid & 3) << 4;
    int ty = tid >> 4, tx = tid & 15;
    float acc[4][4] = {};
    const float* Arow = A + (size_t)(rb * 64 + lr) * n;
    for (int jt = j0; jt < j0 + chunk; jt += 64) {
#pragma unroll
        for (int q = 0; q < 4; q++) {
            f4v av = *(const f4v*)(Arow + jt + lc + (q << 2));
#pragma unroll
            for (int e = 0; e < 4; e++) AtT[lc + (q << 2) + e][lr] = av[e];
        }
#pragma unroll
        for (int q = 0; q < 4; q++) {
            f4v zv = *(const f4v*)(zs + (((size_t)(jt + lr)) << 6) + lc + (q << 2));
            *(f4v*)&Zt[lr][lc + (q << 2)] = zv;
        }
        __syncthreads();
#pragma unroll 4
        for (int k = 0; k < 64; k++) {
            f4v a4 = *(const f4v*)&AtT[k][ty << 2];
            f4v z4 = *(const f4v*)&Zt[k][tx << 2];
#pragma unroll
            for (int r = 0; r < 4; r++)
#pragma unroll
                for (int c = 0; c < 4; c++)
                    acc[r][c] = fmaf(a4[r], z4[c], acc[r][c]);
        }
        __syncthreads();
    }
    float* yp = ypart + ((size_t)ks * n << 6);
#pragma unroll
    for (int r = 0; r < 4; r++) {
        f4v o; o[0] = acc[r][0]; o[1] = acc[r][1]; o[2] = acc[r][2]; o[3] = acc[r][3];
        *(f4v*)(yp + (((size_t)(rb * 64 + (ty << 2) + r)) << 6) + (tx << 2)) = o;
    }
}

// ------- epilogue: H = act(dinv*(sum ypart + 2 zs) + b) [+ score + cnt=0] --
__global__ __launch_bounds__(256) void k_epi(const float* __restrict__ ypart,
                                             const float* __restrict__ zs,
                                             const float* __restrict__ deg,
                                             const float* __restrict__ b,
                                             float* __restrict__ H, int n, int relu,
                                             const float* __restrict__ p,
                                             float* __restrict__ score,
                                             int* __restrict__ cnt) {
    int idx = blockIdx.x * 256 + threadIdx.x;
    int i = idx >> 6, f = idx & 63;
    size_t stride = (size_t)n << 6;
    float y = ypart[idx] + ypart[stride + idx] + ypart[2 * stride + idx] + ypart[3 * stride + idx];
    float di = 1.0f / sqrtf(deg[i] + 2.0f);
    float v = di * (y + 2.0f * zs[idx]) + b[f];
    if (relu) v = fmaxf(v, 0.f);
    H[idx] = v;
    if (p) {   // fused TopK score (identical reduction to the old k_score)
        float pv = p[f];
        float d = v * pv, q = pv * pv;
#pragma unroll
        for (int off = 32; off > 0; off >>= 1) {
            d += __shfl_xor(d, off);
            q += __shfl_xor(q, off);
        }
        if (f == 0) score[i] = tanhf(d / sqrtf(q));
        if (idx < n) cnt[idx] = 0;   // pre-zero CNT for the following topk
    }
}

// ---------------- gather: Mg[r,:] = bf16(A[perm[r],:] + e_{perm[r]}) -------
__global__ __launch_bounds__(256) void k_gather(const float* __restrict__ A,
                                                const int* __restrict__ perm,
                                                __bf16* __restrict__ Mg,
                                                int kbits3 /* log2(K)-3 */) {
    size_t idx8 = (size_t)blockIdx.x * 256 + threadIdx.x;
    int r = (int)(idx8 >> kbits3);
    int c = ((int)idx8 & ((1 << kbits3) - 1)) << 3;
    int K = 1 << (kbits3 + 3);
    int src = perm[r];
    const float* rowp = A + (size_t)src * K + c;
    f4v v0 = *(const f4v*)rowp;
    f4v v1 = *(const f4v*)(rowp + 4);
    bf16x8 t;
#pragma unroll
    for (int j = 0; j < 4; j++) {
        float v = v0[j]; if (src == c + j) v += 1.0f; t[j] = (__bf16)v;
    }
#pragma unroll
    for (int j = 0; j < 4; j++) {
        float v = v1[j]; if (src == c + 4 + j) v += 1.0f; t[4 + j] = (__bf16)v;
    }
    *(bf16x8*)(Mg + idx8 * 8) = t;
}

// ------- pooled aug adjacency: C = Mg @ Mg^T, zero diag, + DEG rowsums -----
// XOR-swizzled LDS: slot (row,seg) holds global chunk (row, seg^(row&7)).
// Read bank = 4*(s^(r&7)) -> 2-way aliasing (free). DEG atomics are exact
// (integer-valued fp32, sums < 2^24 -> order-independent).
template<int BN>
__global__ __launch_bounds__(256) void k_augmm(const __bf16* __restrict__ Mg,
                                               float* __restrict__ C,
                                               float* __restrict__ DEG,
                                               int nk, int K) {
    __shared__ __bf16 At[64 * 64];
    __shared__ __bf16 Bt[BN * 64];
    constexpr int NI = BN / 32;          // B-fragments per wave
    int tid = threadIdx.x;
    int m0 = blockIdx.x * 64, n0 = blockIdx.y * BN;
    int wave = tid >> 6, lane = tid & 63;
    int wm = (wave >> 1) << 5;           // 0 / 32
    int wn = (wave & 1) * (BN >> 1);     // 0 / BN/2
    int quad = lane >> 4, l16 = lane & 15;
    f32x4 acc[2][NI] = {};
    for (int k0 = 0; k0 < K; k0 += 64) {
#pragma unroll
        for (int it = 0; it < 2; it++) {
            int e = it * 256 + tid;
            int row = e >> 3, seg = e & 7;
            int sg = seg ^ (row & 7);
            const __bf16* g = Mg + ((size_t)(m0 + row) * K + k0 + (sg << 3));
            __builtin_amdgcn_global_load_lds(
                (const __attribute__((address_space(1))) void*)g,
                (__attribute__((address_space(3))) void*)(At + (e << 3)), 16, 0, 0);
        }
#pragma unroll
        for (int it = 0; it < BN / 32; it++) {
            int e = it * 256 + tid;
            int row = e >> 3, seg = e & 7;
            int sg = seg ^ (row & 7);
            const __bf16* g = Mg + ((size_t)(n0 + row) * K + k0 + (sg << 3));
            __builtin_amdgcn_global_load_lds(
                (const __attribute__((address_space(1))) void*)g,
                (__attribute__((address_space(3))) void*)(Bt + (e << 3)), 16, 0, 0);
        }
        __syncthreads();
#pragma unroll
        for (int kk = 0; kk < 2; kk++) {
            int s = (kk << 2) + quad;    // 8-elem chunk index 0..7
            bf16x8 af[2], bfm[NI];
#pragma unroll
            for (int im = 0; im < 2; im++) {
                int row = wm + (im << 4) + l16;
                af[im] = *(const bf16x8*)(At + (row << 6) + ((s ^ (row & 7)) << 3));
            }
#pragma unroll
            for (int in2 = 0; in2 < NI; in2++) {
                int row = wn + (in2 << 4) + l16;
                bfm[in2] = *(const bf16x8*)(Bt + (row << 6) + ((s ^ (row & 7)) << 3));
            }
#pragma unroll
            for (int im = 0; im < 2; im++)
#pragma unroll
                for (int in2 = 0; in2 < NI; in2++)
                    acc[im][in2] = __builtin_amdgcn_mfma_f32_16x16x32_bf16(
                        af[im], bfm[in2], acc[im][in2], 0, 0, 0);
        }
        __syncthreads();
    }
    // C/D layout: col = lane&15, row = quad*4 + reg
#pragma unroll
    for (int im = 0; im < 2; im++) {
#pragma unroll
        for (int r = 0; r < 4; r++) {
            int grow = m0 + wm + (im << 4) + (quad << 2) + r;
            float part = 0.f;
#pragma unroll
            for (int in2 = 0; in2 < NI; in2++) {
                int gcol = n0 + wn + (in2 << 4) + l16;
                float v = (grow == gcol) ? 0.f : acc[im][in2][r];
                C[(size_t)grow * nk + gcol] = v;
                part += v;
            }
#pragma unroll
            for (int off = 8; off > 0; off >>= 1) part += __shfl_xor(part, off);
            if (l16 == 0) atomicAdd(&DEG[grow], part);
        }
    }
}

// ---------------- parallel top-k -------------------------------------------
__global__ __launch_bounds__(256) void k_topk_count(const float* __restrict__ score,
                                                    int* __restrict__ cnt, int n) {
    __shared__ float sc[256];
    int j0 = blockIdx.y * 256;
    sc[threadIdx.x] = score[j0 + threadIdx.x];
    int i = blockIdx.x * 256 + threadIdx.x;
    float si = score[i];
    __syncthreads();
    int c = 0;
#pragma unroll 8
    for (int t = 0; t < 256; t++) {
        float sj = sc[t];
        int j = j0 + t;
        c += ((sj > si) || (sj == si && j < i)) ? 1 : 0;
    }
    atomicAdd(&cnt[i], c);
}
// rank<k -> perm[rank]=i; inv[i]=rank or -1; zero DEG of the next level.
__global__ __launch_bounds__(256) void k_topk_scatter(const int* __restrict__ cnt,
                                                      int* __restrict__ perm,
                                                      int* __restrict__ inv,
                                                      float* __restrict__ degN,
                                                      int k) {
    int i = blockIdx.x * 256 + threadIdx.x;
    int c = cnt[i];
    if (c < k) perm[c] = i;
    inv[i] = (c < k) ? c : -1;
    if (i < k) degN[i] = 0.f;
}

// ---------------- final: out = relu(h)/(1-prob) @ fc_w + fc_b --------------
__global__ __launch_bounds__(256) void k_final(const float* __restrict__ H,
                                               const float* __restrict__ prob,
                                               const float* __restrict__ fcw,
                                               const float* __restrict__ fcb,
                                               float* __restrict__ out, int n) {
    int wave = threadIdx.x >> 6, lane = threadIdx.x & 63;
    int row = (blockIdx.x << 2) + wave;
    float scale = 1.0f / (1.0f - prob[0]);
    float h = fmaxf(H[((size_t)row << 6) + lane], 0.f);
    float v = h * fcw[lane];
#pragma unroll
    for (int off = 32; off > 0; off >>= 1) v += __shfl_xor(v, off);
    if (lane == 0) out[row] = v * scale + fcb[0];
}

// ===========================================================================
extern "C" void kernel_launch(void* const* d_in, const int* in_sizes, int n_in,
                              void* d_out, int out_size, void* d_ws, size_t ws_size,
                              hipStream_t stream) {
    (void)in_sizes; (void)n_in; (void)out_size;
    const float* x     = (const float*)d_in[0];
    const float* adj   = (const float*)d_in[1];
    const float* prob  = (const float*)d_in[2];
    const float* downW = (const float*)d_in[3];
    const float* downb = (const float*)d_in[4];
    const float* poolw = (const float*)d_in[5];
    const float* upW   = (const float*)d_in[6];
    const float* upb   = (const float*)d_in[7];
    const float* fcw   = (const float*)d_in[8];
    const float* fcb   = (const float*)d_in[9];

    char* ws = (char*)d_ws;
    __bf16* MG   = (__bf16*)(ws + 0);           // 16 MB
    float* A1    = (float*)(ws + 16777216);     // 16 MB
    float* A2    = (float*)(ws + 33554432);     // 4 MB
    float* A3    = (float*)(ws + 37748736);     // 1 MB
    float* H0    = (float*)(ws + 38797312);     // 1 MB
    float* H1    = (float*)(ws + 39845888);     // 512 KB
    float* H2    = (float*)(ws + 40370176);     // 256 KB
    float* H3    = (float*)(ws + 40632320);     // 128 KB
    float* ZS    = (float*)(ws + 40763392);     // 1 MB
    float* YP    = (float*)(ws + 41811968);     // 4 MB
    float* UA    = (float*)(ws + 46006272);     // 1 MB  (up outputs, ping)
    float* UB    = (float*)(ws + 47054848);     // 512 KB (up outputs, pong)
    float* DEG0  = (float*)(ws + 47579136);     // 16 KB
    float* DEG1  = (float*)(ws + 47595520);     // 8 KB
    float* DEG2  = (float*)(ws + 47603712);     // 4 KB
    float* DEG3  = (float*)(ws + 47607808);     // 2 KB
    float* SCORE = (float*)(ws + 47609856);     // 16 KB
    int*   PERM0 = (int*)(ws + 47626240);       // 8 KB
    int*   PERM1 = (int*)(ws + 47634432);       // 4 KB
    int*   PERM2 = (int*)(ws + 47638528);       // 2 KB
    int*   INV0  = (int*)(ws + 47640576);       // 16 KB
    int*   INV1  = (int*)(ws + 47656960);       // 8 KB
    int*   INV2  = (int*)(ws + 47665152);       // 4 KB
    int*   CNT   = (int*)(ws + 47669248);       // 16 KB
    if (ws_size < (size_t)47685632) return;

    // ---------------- down level 0 ----------------
    k_rowsum<<<NN0, 256, 0, stream>>>(adj, DEG0, NN0);
    k_zs<<<NN0 / 4, 256, 0, stream>>>(x, downW, DEG0, ZS, NN0);
    k_prop<<<dim3(NN0 / 64, 4), 256, 0, stream>>>(adj, ZS, YP, NN0);
    k_epi<<<NN0 / 4, 256, 0, stream>>>(YP, ZS, DEG0, downb, H0, NN0, 1,
                                       poolw + 0, SCORE, CNT);
    // pool 0 -> 1
    k_topk_count<<<dim3(NN0 / 256, NN0 / 256), 256, 0, stream>>>(SCORE, CNT, NN0);
    k_topk_scatter<<<NN0 / 256, 256, 0, stream>>>(CNT, PERM0, INV0, DEG1, NN1);
    k_gather<<<(NN1 * NN0 / 8) / 256, 256, 0, stream>>>(adj, PERM0, MG, 9);
    k_augmm<128><<<dim3(NN1 / 64, NN1 / 128), 256, 0, stream>>>(MG, A1, DEG1, NN1, NN0);
    // ---------------- down level 1 ----------------
    k_zs_pool<<<NN1 / 4, 256, 0, stream>>>(H0, SCORE, PERM0, downW + 4096, DEG1, ZS);
    k_prop<<<dim3(NN1 / 64, 4), 256, 0, stream>>>(A1, ZS, YP, NN1);
    k_epi<<<NN1 / 4, 256, 0, stream>>>(YP, ZS, DEG1, downb + 64, H1, NN1, 1,
                                       poolw + 64, SCORE, CNT);
    // pool 1 -> 2
    k_topk_count<<<dim3(NN1 / 256, NN1 / 256), 256, 0, stream>>>(SCORE, CNT, NN1);
    k_topk_scatter<<<NN1 / 256, 256, 0, stream>>>(CNT, PERM1, INV1, DEG2, NN2);
    k_gather<<<(NN2 * NN1 / 8) / 256, 256, 0, stream>>>(A1, PERM1, MG, 8);
    k_augmm<64><<<dim3(NN2 / 64, NN2 / 64), 256, 0, stream>>>(MG, A2, DEG2, NN2, NN1);
    // ---------------- down level 2 ----------------
    k_zs_pool<<<NN2 / 4, 256, 0, stream>>>(H1, SCORE, PERM1, downW + 2 * 4096, DEG2, ZS);
    k_prop<<<dim3(NN2 / 64, 4), 256, 0, stream>>>(A2, ZS, YP, NN2);
    k_epi<<<NN2 / 4, 256, 0, stream>>>(YP, ZS, DEG2, downb + 2 * 64, H2, NN2, 1,
                                       poolw + 128, SCORE, CNT);
    // pool 2 -> 3
    k_topk_count<<<dim3(NN2 / 256, NN2 / 256), 256, 0, stream>>>(SCORE, CNT, NN2);
    k_topk_scatter<<<NN2 / 256, 256, 0, stream>>>(CNT, PERM2, INV2, DEG3, NN3);
    k_gather<<<(NN3 * NN2 / 8) / 256, 256, 0, stream>>>(A2, PERM2, MG, 7);
    k_augmm<64><<<dim3(NN3 / 64, NN3 / 64), 256, 0, stream>>>(MG, A3, DEG3, NN3, NN2);
    // ---------------- down level 3 ----------------
    k_zs_pool<<<NN3 / 4, 256, 0, stream>>>(H2, SCORE, PERM2, downW + 3 * 4096, DEG3, ZS);
    k_prop<<<dim3(NN3 / 64, 4), 256, 0, stream>>>(A3, ZS, YP, NN3);
    k_epi<<<NN3 / 4, 256, 0, stream>>>(YP, ZS, DEG3, downb + 3 * 64, H3, NN3, 1,
                                       nullptr, nullptr, nullptr);

    // ---------------- up sweep ----------------
    // i=0: res=H2 (1024), A=A2, inv=INV2, incoming H3 -> UA
    k_zs_unpool<<<NN2 / 4, 256, 0, stream>>>(H2, H3, INV2, upW, DEG2, ZS);
    k_prop<<<dim3(NN2 / 64, 4), 256, 0, stream>>>(A2, ZS, YP, NN2);
    k_epi<<<NN2 / 4, 256, 0, stream>>>(YP, ZS, DEG2, upb, UA, NN2, 1,
                                       nullptr, nullptr, nullptr);
    // i=1: res=H1 (2048), A=A1, inv=INV1, incoming UA -> UB
    k_zs_unpool<<<NN1 / 4, 256, 0, stream>>>(H1, UA, INV1, upW + 4096, DEG1, ZS);
    k_prop<<<dim3(NN1 / 64, 4), 256, 0, stream>>>(A1, ZS, YP, NN1);
    k_epi<<<NN1 / 4, 256, 0, stream>>>(YP, ZS, DEG1, upb + 64, UB, NN1, 1,
                                       nullptr, nullptr, nullptr);
    // i=2: res=H0 (4096), A=adj, inv=INV0, incoming UB -> UA (no relu)
    k_zs_unpool<<<NN0 / 4, 256, 0, stream>>>(H0, UB, INV0, upW + 2 * 4096, DEG0, ZS);
    k_prop<<<dim3(NN0 / 64, 4), 256, 0, stream>>>(adj, ZS, YP, NN0);
    k_epi<<<NN0 / 4, 256, 0, stream>>>(YP, ZS, DEG0, upb + 2 * 64, UA, NN0, 0,
                                       nullptr, nullptr, nullptr);

    // final: relu + dropout(p=0) scale + linear head
    k_final<<<NN0 / 4, 256, 0, stream>>>(UA, prob, fcw, fcb, (float*)d_out, NN0);
}